// Round 7
// baseline (423.575 us; speedup 1.0000x reference)
//
#include <hip/hip_runtime.h>

// B=4, S=2048, D=1024, H=16, Dh=64
// Outputs: [0, 8388608) = outs [B,S,D] fp32 ; [8388608, 16777216) = res2 [H,B,S,Dh] fp32

typedef __attribute__((ext_vector_type(8))) short bf16x8;
typedef __attribute__((ext_vector_type(4))) short bf16x4;
typedef __attribute__((ext_vector_type(4))) float f32x4;

#define MFMA32(a, b, c) __builtin_amdgcn_mfma_f32_16x16x32_bf16(a, b, c, 0, 0, 0)

#define GLDS16(g, l)                                                                       \
  __builtin_amdgcn_global_load_lds((const __attribute__((address_space(1))) void*)(g),     \
                                   (__attribute__((address_space(3))) void*)(l), 16, 0, 0)

static __device__ __forceinline__ float fast_exp2(float x) {
#if __has_builtin(__builtin_amdgcn_exp2f)
  return __builtin_amdgcn_exp2f(x);
#else
  return __expf(x * 0.69314718056f);
#endif
}

__device__ __forceinline__ unsigned short fbf(float f) {
  union { float f; unsigned u; } x; x.f = f;
  unsigned r = x.u + 0x7fffu + ((x.u >> 16) & 1u);   // RNE
  return (unsigned short)(r >> 16);
}

static __device__ __forceinline__ bf16x4 pack2(unsigned lo, unsigned hi) {
  union { unsigned u[2]; bf16x4 v; } x; x.u[0] = lo; x.u[1] = hi; return x.v;
}

static __device__ __forceinline__ bf16x8 cat2(bf16x4 lo, bf16x4 hi) {
  union { bf16x4 h[2]; bf16x8 v; } x; x.h[0] = lo; x.h[1] = hi; return x.v;
}

// exp2 on 4 S-values, round to bf16, apply 4 mask bits (pre-shifted word), pack to bf16x4
static __device__ __forceinline__ bf16x4 epp(f32x4 s, unsigned pre, int sh) {
  union { float f; unsigned u; } e0, e1, e2, e3;
  e0.f = fast_exp2(s[0]); e1.f = fast_exp2(s[1]);
  e2.f = fast_exp2(s[2]); e3.f = fast_exp2(s[3]);
  unsigned p01 = __builtin_amdgcn_perm(e1.u + 0x8000u, e0.u + 0x8000u, 0x07060302u);
  unsigned p23 = __builtin_amdgcn_perm(e3.u + 0x8000u, e2.u + 0x8000u, 0x07060302u);
  int m0 = __builtin_amdgcn_sbfe(pre, sh + 0, 1), m1 = __builtin_amdgcn_sbfe(pre, sh + 1, 1);
  int m2 = __builtin_amdgcn_sbfe(pre, sh + 2, 1), m3 = __builtin_amdgcn_sbfe(pre, sh + 3, 1);
  unsigned k01 = __builtin_amdgcn_perm((unsigned)m1, (unsigned)m0, 0x07060100u);
  unsigned k23 = __builtin_amdgcn_perm((unsigned)m3, (unsigned)m2, 0x07060100u);
  return pack2(p01 & k01, p23 & k23);
}

// ---------------- merged fp32 -> bf16 convert pass: q,k,v (8192x3 blocks) + 4 weights ----------------
__global__ __launch_bounds__(256) void prep_kernel(const float* __restrict__ s0,
                                                   const float* __restrict__ s1,
                                                   const float* __restrict__ s2,
                                                   const float* __restrict__ w0,
                                                   const float* __restrict__ w1,
                                                   const float* __restrict__ w2,
                                                   const float* __restrict__ w3,
                                                   unsigned short* __restrict__ d0,
                                                   unsigned short* __restrict__ d1,
                                                   unsigned short* __restrict__ d2,
                                                   unsigned short* __restrict__ e0,
                                                   unsigned short* __restrict__ e1,
                                                   unsigned short* __restrict__ e2,
                                                   unsigned short* __restrict__ e3) {
  int bid = blockIdx.x;
  const float* s;
  unsigned short* d;
  int i;
  if (bid < 24576) {  // q,k,v: 3 x 8192 blocks
    int z = bid >> 13;
    s = (z == 0) ? s0 : (z == 1) ? s1 : s2;
    d = (z == 0) ? d0 : (z == 1) ? d1 : d2;
    i = (bid & 8191) * 256 + threadIdx.x;
  } else {            // weights: 4 x 1024 blocks
    int r = bid - 24576;
    int z = r >> 10;
    s = (z == 0) ? w0 : (z == 1) ? w1 : (z == 2) ? w2 : w3;
    d = (z == 0) ? e0 : (z == 1) ? e1 : (z == 2) ? e2 : e3;
    i = (r & 1023) * 256 + threadIdx.x;
  }
  float4 v = ((const float4*)s)[i];
  ushort4 o;
  o.x = fbf(v.x); o.y = fbf(v.y); o.z = fbf(v.z); o.w = fbf(v.w);
  ((ushort4*)d)[i] = o;
}

// ---------------- mask int32 -> bitmask, kt-major: o[(kt*8192+row)*2 + h] ----------------
__global__ __launch_bounds__(256) void pack_mask_kernel(const int* __restrict__ m,
                                                        unsigned long long* __restrict__ o) {
  int i = blockIdx.x * 256 + threadIdx.x;
  unsigned long long b = __ballot(m[i] != 0);
  if ((threadIdx.x & 63) == 0) {
    int row = i >> 11;          // [B*S) row index
    int kt = (i >> 7) & 15;     // 128-kcol tile
    int h = (i >> 6) & 1;       // ull half within tile
    o[(kt * 8192 + row) * 2 + h] = b;
  }
}

// ---------------- V [B,H,S',Dh] (natural GEMM out) -> Vt [B,H,Dh,S'] transpose ----------------
// (the flat [S,D] slab viewed as [H][2048][64] IS the reference reshape; this kernel
// only transposes [s'][dh] -> [dh][s'] per (b,h). Fusing into proj is impossible
// without scatter: a 128x128 GEMM tile owns only length-2 runs along s'.)
__global__ __launch_bounds__(256) void vtrans_kernel(const unsigned short* __restrict__ Vf,
                                                     unsigned short* __restrict__ Vt) {
  __shared__ unsigned short T[64][72];
  const int bh = blockIdx.y;
  const int s0 = blockIdx.x * 64;
  const int tid = threadIdx.x;
  {
    int r = tid >> 2, c = (tid & 3) * 16;
    const unsigned short* src = Vf + bh * 131072 + (s0 + r) * 64 + c;
    uint4 v0 = *(const uint4*)(src);
    uint4 v1 = *(const uint4*)(src + 8);
    *(uint4*)&T[r][c] = v0;
    *(uint4*)&T[r][c + 8] = v1;
  }
  __syncthreads();
  {
    int dh = tid & 63, rb = (tid >> 6) * 16;
    unsigned short o[16];
#pragma unroll
    for (int j = 0; j < 16; ++j) o[j] = T[rb + j][dh];
    unsigned short* dst = Vt + bh * 131072 + dh * 2048 + s0 + rb;
    *(uint4*)dst = *(const uint4*)&o[0];
    *(uint4*)(dst + 8) = *(const uint4*)&o[8];
  }
}

// ---------------- fused projections: C = A * W^T for z in {Q,K,V} ----------------
// T3-minimum pipeline: double-buffered LDS (BK=32), next-tile global_load_lds issued
// BEFORE the current tile's MFMA block, ONE __syncthreads per tile (vmcnt drain lands
// after the MFMA phase has hidden the load latency).
// z=0: Qf bf16 scaled by log2(e)/8 ; z=1: Kf ; z=2: Vnat (natural layout; pure reshape)
__global__ __launch_bounds__(256) void proj_kernel(const unsigned short* __restrict__ A0,
                                                   const unsigned short* __restrict__ A1,
                                                   const unsigned short* __restrict__ A2,
                                                   const unsigned short* __restrict__ W0,
                                                   const unsigned short* __restrict__ W1,
                                                   const unsigned short* __restrict__ W2,
                                                   unsigned short* __restrict__ C0,
                                                   unsigned short* __restrict__ C1,
                                                   unsigned short* __restrict__ C2) {
  __shared__ unsigned short Al[2][128 * 32];  // 2 x 8KB
  __shared__ unsigned short Bl[2][128 * 32];  // 2 x 8KB
  // XCD-aware swizzle: nwg = 1536 -> wid = (flat%8)*192 + flat/8 (by-strips stay on one XCD)
  const int flat = (blockIdx.z * 64 + blockIdx.y) * 8 + blockIdx.x;
  const int wid = (flat & 7) * 192 + (flat >> 3);
  const int z = wid >> 9;
  const int by = (wid >> 3) & 63;
  const int bx = wid & 7;
  const unsigned short* A = (z == 0) ? A0 : (z == 1) ? A1 : A2;
  const unsigned short* B = (z == 0) ? W0 : (z == 1) ? W1 : W2;
  const int tid = threadIdx.x;
  const int w = tid >> 6, l = tid & 63, q4 = l >> 4, c16 = l & 15;
  const int wm = w & 1, wn = w >> 1;
  const int mBase = by * 128, nBase = bx * 128;

  f32x4 acc[4][4];
#pragma unroll
  for (int a0 = 0; a0 < 4; ++a0)
#pragma unroll
    for (int a1 = 0; a1 < 4; ++a1) acc[a0][a1] = (f32x4){0.f, 0.f, 0.f, 0.f};

  const int r0 = tid >> 2, cc0 = tid & 3;
  const unsigned short* ga0 = A + (mBase + r0) * 1024 + cc0 * 8;
  const unsigned short* ga1 = A + (mBase + 64 + r0) * 1024 + cc0 * 8;
  const unsigned short* gb0 = B + (nBase + r0) * 1024 + cc0 * 8;
  const unsigned short* gb1 = B + (nBase + 64 + r0) * 1024 + cc0 * 8;

  // prologue: stage tile 0 into buffer 0
  GLDS16(ga0, &Al[0][tid * 8]);
  GLDS16(ga1, &Al[0][(tid + 256) * 8]);
  GLDS16(gb0, &Bl[0][tid * 8]);
  GLDS16(gb1, &Bl[0][(tid + 256) * 8]);
  __syncthreads();

  int cur = 0;
  for (int kt = 0; kt < 32; ++kt) {
    if (kt < 31) {  // prefetch next tile into the other buffer (hides under MFMA below)
      int ko = (kt + 1) * 32;
      GLDS16(ga0 + ko, &Al[cur ^ 1][tid * 8]);
      GLDS16(ga1 + ko, &Al[cur ^ 1][(tid + 256) * 8]);
      GLDS16(gb0 + ko, &Bl[cur ^ 1][tid * 8]);
      GLDS16(gb1 + ko, &Bl[cur ^ 1][(tid + 256) * 8]);
    }
    bf16x8 af[4], bfr[4];
#pragma unroll
    for (int mi = 0; mi < 4; ++mi)
      af[mi] = *(const bf16x8*)&Al[cur][(wm * 64 + mi * 16 + c16) * 32 + q4 * 8];
#pragma unroll
    for (int ni = 0; ni < 4; ++ni)
      bfr[ni] = *(const bf16x8*)&Bl[cur][(wn * 64 + ni * 16 + c16) * 32 + q4 * 8];
#pragma unroll
    for (int mi = 0; mi < 4; ++mi)
#pragma unroll
      for (int ni = 0; ni < 4; ++ni) acc[mi][ni] = MFMA32(af[mi], bfr[ni], acc[mi][ni]);
    __syncthreads();  // drains prefetch vmcnt + guards buffer reuse
    cur ^= 1;
  }

  unsigned short* C = (z == 0) ? C0 : (z == 1) ? C1 : C2;
  const float scale = (z == 0) ? 0.18033688f : 1.0f;  // log2(e)/8 folded into Q
#pragma unroll
  for (int mi = 0; mi < 4; ++mi) {
#pragma unroll
    for (int ni = 0; ni < 4; ++ni) {
#pragma unroll
      for (int rg = 0; rg < 4; ++rg) {
        int row = mBase + wm * 64 + mi * 16 + q4 * 4 + rg;
        int col = nBase + wn * 64 + ni * 16 + c16;
        C[row * 1024 + col] = fbf(acc[mi][ni][rg] * scale);
      }
    }
  }
}

// ---------------- final GEMM: out = Cws * fc_w^T + bias (fp32 out), pipelined ----------------
__global__ __launch_bounds__(256) void gemm_out(const unsigned short* __restrict__ A,
                                                const unsigned short* __restrict__ B,
                                                float* __restrict__ C,
                                                const float* __restrict__ bias) {
  __shared__ unsigned short Al[2][128 * 32];
  __shared__ unsigned short Bl[2][128 * 32];
  const int flat = blockIdx.y * 8 + blockIdx.x;
  const int wid = (flat & 7) * 64 + (flat >> 3);
  const int by = wid >> 3, bx = wid & 7;
  const int tid = threadIdx.x;
  const int w = tid >> 6, l = tid & 63, q4 = l >> 4, c16 = l & 15;
  const int wm = w & 1, wn = w >> 1;
  const int mBase = by * 128, nBase = bx * 128;

  f32x4 acc[4][4];
#pragma unroll
  for (int a0 = 0; a0 < 4; ++a0)
#pragma unroll
    for (int a1 = 0; a1 < 4; ++a1) acc[a0][a1] = (f32x4){0.f, 0.f, 0.f, 0.f};

  const int r0 = tid >> 2, cc0 = tid & 3;
  const unsigned short* ga0 = A + (mBase + r0) * 1024 + cc0 * 8;
  const unsigned short* ga1 = A + (mBase + 64 + r0) * 1024 + cc0 * 8;
  const unsigned short* gb0 = B + (nBase + r0) * 1024 + cc0 * 8;
  const unsigned short* gb1 = B + (nBase + 64 + r0) * 1024 + cc0 * 8;

  GLDS16(ga0, &Al[0][tid * 8]);
  GLDS16(ga1, &Al[0][(tid + 256) * 8]);
  GLDS16(gb0, &Bl[0][tid * 8]);
  GLDS16(gb1, &Bl[0][(tid + 256) * 8]);
  __syncthreads();

  int cur = 0;
  for (int kt = 0; kt < 32; ++kt) {
    if (kt < 31) {
      int ko = (kt + 1) * 32;
      GLDS16(ga0 + ko, &Al[cur ^ 1][tid * 8]);
      GLDS16(ga1 + ko, &Al[cur ^ 1][(tid + 256) * 8]);
      GLDS16(gb0 + ko, &Bl[cur ^ 1][tid * 8]);
      GLDS16(gb1 + ko, &Bl[cur ^ 1][(tid + 256) * 8]);
    }
    bf16x8 af[4], bfr[4];
#pragma unroll
    for (int mi = 0; mi < 4; ++mi)
      af[mi] = *(const bf16x8*)&Al[cur][(wm * 64 + mi * 16 + c16) * 32 + q4 * 8];
#pragma unroll
    for (int ni = 0; ni < 4; ++ni)
      bfr[ni] = *(const bf16x8*)&Bl[cur][(wn * 64 + ni * 16 + c16) * 32 + q4 * 8];
#pragma unroll
    for (int mi = 0; mi < 4; ++mi)
#pragma unroll
      for (int ni = 0; ni < 4; ++ni) acc[mi][ni] = MFMA32(af[mi], bfr[ni], acc[mi][ni]);
    __syncthreads();
    cur ^= 1;
  }

#pragma unroll
  for (int mi = 0; mi < 4; ++mi) {
#pragma unroll
    for (int ni = 0; ni < 4; ++ni) {
#pragma unroll
      for (int rg = 0; rg < 4; ++rg) {
        int row = mBase + wm * 64 + mi * 16 + q4 * 4 + rg;
        int col = nBase + wn * 64 + ni * 16 + c16;
        C[row * 1024 + col] = acc[mi][ni][rg] + bias[col];
      }
    }
  }
}

// ---------------- flash attention per (b, h, 128-row q tile) ----------------
// S^T = K·Q^T (P stays in registers); O^T = Vt·P^T with K=32 MFMA via k-permutation:
// lane q4 natively holds kcols {32m+4q4+j, 32m+16+4q4+j}; Vt A-frag loads the
// sigma-matched pair of b64s. Row sums via constant ones A-frag (permutation-invariant).
__global__ __launch_bounds__(256, 4) void flash_kernel(const unsigned short* __restrict__ Q,
                                                       const unsigned short* __restrict__ K,
                                                       const unsigned short* __restrict__ Vt,
                                                       const uint4* __restrict__ mb,
                                                       unsigned short* __restrict__ Cws,
                                                       float* __restrict__ res2) {
  __shared__ unsigned short Klds[128 * 64];   // [kcol][granule ^ (kcol&7)]
  __shared__ unsigned short Vtlds[64 * 128];  // [dh][granule ^ (dh&15)]
  const int tid = threadIdx.x;
  const int w = tid >> 6, l = tid & 63, q4 = l >> 4, c16 = l & 15;
  const int q44 = q4 * 4;
  // XCD swizzle: nwg = 1024 -> wid = (flat%8)*128 + flat/8 ; qt-groups (shared K/V) co-XCD
  const int flat = (blockIdx.z * 16 + blockIdx.y) * 16 + blockIdx.x;
  const int wid = (flat & 7) * 128 + (flat >> 3);
  const int qt = wid & 15, h = (wid >> 4) & 15, b = wid >> 8;
  const unsigned short* Qh = Q + (b * 2048 + h * 128) * 1024;
  const unsigned short* Kh = K + (b * 2048 + h * 128) * 1024;
  const unsigned short* Vth = Vt + (b * 16 + h) * 64 * 2048;

  // Q B-frags in registers for all 16 K-tiles
  bf16x8 qf[2][2];
#pragma unroll
  for (int i = 0; i < 2; ++i)
#pragma unroll
    for (int kc = 0; kc < 2; ++kc)
      qf[i][kc] = *(const bf16x8*)(Qh + (qt * 128 + w * 32 + i * 16 + c16) * 64 + kc * 32 + q4 * 8);

  const int rowi = b * 2048 + qt * 128 + w * 32 + c16;  // mask row, i=0 (i=1: +16)

  // staging lane offsets (global side carries the swizzle; LDS side is lane-linear)
  const int kOff = (tid >> 3) * 64 + (((tid & 7) ^ ((tid >> 3) & 7)) * 8);
  const int vOff = (tid >> 4) * 2048 + (((tid & 15) ^ (tid >> 4)) * 8);

  // QK read lane base: row=16n+c16, phys granule q4^(c16&7) (content = global granule q4)
  const int kb0 = c16 * 64 + ((q4 ^ (c16 & 7)) * 8);
  const int kb1 = kb0 ^ 32;
  // PV read: row=16t+c16, global granule gLo=4m+(q4>>1) (hi: +2), phys = g ^ c16, half q4&1
  const int vb = c16 * 128 + (q4 & 1) * 4;
  const int q41 = q4 >> 1;

  const bf16x8 ones8 = {(short)0x3F80, (short)0x3F80, (short)0x3F80, (short)0x3F80,
                        (short)0x3F80, (short)0x3F80, (short)0x3F80, (short)0x3F80};

  f32x4 oacc[2][4], soacc[2];
#pragma unroll
  for (int i = 0; i < 2; ++i) {
    soacc[i] = (f32x4){0.f, 0.f, 0.f, 0.f};
#pragma unroll
    for (int t = 0; t < 4; ++t) oacc[i][t] = (f32x4){0.f, 0.f, 0.f, 0.f};
  }

  for (int kt = 0; kt < 16; ++kt) {
    const unsigned short* gk = Kh + kt * 8192 + kOff;
    const unsigned short* gv = Vth + kt * 128 + vOff;
#pragma unroll
    for (int j = 0; j < 4; ++j) {
      GLDS16(gk + j * 2048, &Klds[(j * 256 + tid) * 8]);
      GLDS16(gv + j * 32768, &Vtlds[(j * 256 + tid) * 8]);
    }
    // coalesced kt-major mask load (overlaps the DMA)
    uint4 m0 = mb[kt * 8192 + rowi];
    uint4 m1 = mb[kt * 8192 + rowi + 16];
    unsigned pre0[4] = {m0.x >> q44, m0.y >> q44, m0.z >> q44, m0.w >> q44};
    unsigned pre1[4] = {m1.x >> q44, m1.y >> q44, m1.z >> q44, m1.w >> q44};
    __syncthreads();

#pragma unroll
    for (int m = 0; m < 4; ++m) {  // pair of 16-kcol chunks: n = 2m, 2m+1
      bf16x8 kfE0 = *(const bf16x8*)(Klds + kb0 + (2 * m) * 1024);
      bf16x8 kfE1 = *(const bf16x8*)(Klds + kb1 + (2 * m) * 1024);
      bf16x8 kfO0 = *(const bf16x8*)(Klds + kb0 + (2 * m + 1) * 1024);
      bf16x8 kfO1 = *(const bf16x8*)(Klds + kb1 + (2 * m + 1) * 1024);
      f32x4 sE0 = {0.f, 0.f, 0.f, 0.f}, sE1 = {0.f, 0.f, 0.f, 0.f};
      f32x4 sO0 = {0.f, 0.f, 0.f, 0.f}, sO1 = {0.f, 0.f, 0.f, 0.f};
      sE0 = MFMA32(kfE0, qf[0][0], sE0); sE0 = MFMA32(kfE1, qf[0][1], sE0);
      sE1 = MFMA32(kfE0, qf[1][0], sE1); sE1 = MFMA32(kfE1, qf[1][1], sE1);
      sO0 = MFMA32(kfO0, qf[0][0], sO0); sO0 = MFMA32(kfO1, qf[0][1], sO0);
      sO1 = MFMA32(kfO0, qf[1][0], sO1); sO1 = MFMA32(kfO1, qf[1][1], sO1);

      int shE = 0, shO = 16;  // kcol bit position within 32-bit mask word m
      bf16x8 pf0 = cat2(epp(sE0, pre0[m], shE), epp(sO0, pre0[m], shO));
      bf16x8 pf1 = cat2(epp(sE1, pre1[m], shE), epp(sO1, pre1[m], shO));

      int pLo = (4 * m + q41) ^ c16;
      int aLo = vb + pLo * 8;
#pragma unroll
      for (int t = 0; t < 4; ++t) {
        bf16x4 vlo = *(const bf16x4*)(Vtlds + aLo + t * 2048);
        bf16x4 vhi = *(const bf16x4*)(Vtlds + (aLo ^ 16) + t * 2048);
        bf16x8 vf8 = cat2(vlo, vhi);
        oacc[0][t] = MFMA32(vf8, pf0, oacc[0][t]);
        oacc[1][t] = MFMA32(vf8, pf1, oacc[1][t]);
      }
      soacc[0] = MFMA32(ones8, pf0, soacc[0]);
      soacc[1] = MFMA32(ones8, pf1, soacc[1]);
    }
    __syncthreads();
  }

  // epilogue: lane (c16,q4) holds O[q=base+i*16+c16][dh=16t+q44+rg]; soacc = rowsum(q)
#pragma unroll
  for (int i = 0; i < 2; ++i) {
    float sum = soacc[i][0];
    float rcp = (sum > 0.f) ? (1.0f / sum) : 0.f;  // sum==0 -> 0 reproduces NaN->0
    int q = qt * 128 + w * 32 + i * 16 + c16;
    float* rp = res2 + (((h * 4 + b) * 2048 + q) * 64 + q44);
    unsigned short* cp = Cws + ((b * 2048 + q) * 1024 + h * 64 + q44);
#pragma unroll
    for (int t = 0; t < 4; ++t) {
      float o0 = oacc[i][t][0] * rcp, o1 = oacc[i][t][1] * rcp;
      float o2 = oacc[i][t][2] * rcp, o3 = oacc[i][t][3] * rcp;
      float4 fo = {o0, o1, o2, o3};
      *(float4*)(rp + t * 16) = fo;
      ushort4 cv = {fbf(o0), fbf(o1), fbf(o2), fbf(o3)};
      *(ushort4*)(cp + t * 16) = cv;
    }
  }
}

extern "C" void kernel_launch(void* const* d_in, const int* in_sizes, int n_in,
                              void* d_out, int out_size, void* d_ws, size_t ws_size,
                              hipStream_t stream) {
  const float* query = (const float*)d_in[0];
  const float* key_t = (const float*)d_in[1];
  const float* value = (const float*)d_in[2];
  const int* mask = (const int*)d_in[3];
  const float* Wq = (const float*)d_in[4];
  const float* Wk = (const float*)d_in[5];
  const float* Wv = (const float*)d_in[6];
  const float* fcw = (const float*)d_in[7];
  const float* fcb = (const float*)d_in[8];
  float* out = (float*)d_out;

  char* ws = (char*)d_ws;
  unsigned short* qbf = (unsigned short*)(ws);                      // 16MB (later: Cws)
  unsigned short* kbf = (unsigned short*)(ws + (16u << 20));        // 16MB (later: mask bits)
  unsigned short* vbf = (unsigned short*)(ws + (32u << 20));        // 16MB (later: Vt)
  unsigned short* wqb = (unsigned short*)(ws + (48u << 20));        // 2MB
  unsigned short* wkb = (unsigned short*)(ws + (50u << 20));
  unsigned short* wvb = (unsigned short*)(ws + (52u << 20));
  unsigned short* fwb = (unsigned short*)(ws + (54u << 20));
  unsigned short* Qf = (unsigned short*)(ws + (56u << 20));         // 16MB
  unsigned short* Kf = (unsigned short*)(ws + (72u << 20));         // 16MB
  unsigned short* Vnat = (unsigned short*)(ws + (88u << 20));       // 16MB; total 104MB
  unsigned short* Cws = qbf;                                        // alias (qbf dead after proj)
  unsigned long long* mbits = (unsigned long long*)kbf;             // alias (kbf dead after proj)
  unsigned short* Vt = vbf;                                         // alias (vbf dead after proj)

  prep_kernel<<<28672, 256, 0, stream>>>(query, key_t, value, Wq, Wk, Wv, fcw,
                                         qbf, kbf, vbf, wqb, wkb, wvb, fwb);

  proj_kernel<<<dim3(8, 64, 3), 256, 0, stream>>>(qbf, kbf, vbf, wqb, wkb, wvb,
                                                  Qf, Kf, Vnat);

  vtrans_kernel<<<dim3(32, 64), 256, 0, stream>>>(Vnat, Vt);

  pack_mask_kernel<<<65536, 256, 0, stream>>>(mask, mbits);

  flash_kernel<<<dim3(16, 16, 4), 256, 0, stream>>>(Qf, Kf, Vt, (const uint4*)mbits, Cws,
                                                    out + 8388608);

  gemm_out<<<dim3(8, 64), 256, 0, stream>>>(Cws, fwb, out, fcb);
}

// Round 8
// 404.818 us; speedup vs baseline: 1.0463x; 1.0463x over previous
//
#include <hip/hip_runtime.h>

// B=4, S=2048, D=1024, H=16, Dh=64
// Outputs: [0, 8388608) = outs [B,S,D] fp32 ; [8388608, 16777216) = res2 [H,B,S,Dh] fp32

typedef __attribute__((ext_vector_type(8))) short bf16x8;
typedef __attribute__((ext_vector_type(4))) short bf16x4;
typedef __attribute__((ext_vector_type(4))) float f32x4;

#define MFMA32(a, b, c) __builtin_amdgcn_mfma_f32_16x16x32_bf16(a, b, c, 0, 0, 0)

#define GLDS16(g, l)                                                                       \
  __builtin_amdgcn_global_load_lds((const __attribute__((address_space(1))) void*)(g),     \
                                   (__attribute__((address_space(3))) void*)(l), 16, 0, 0)

static __device__ __forceinline__ float fast_exp2(float x) {
#if __has_builtin(__builtin_amdgcn_exp2f)
  return __builtin_amdgcn_exp2f(x);
#else
  return __expf(x * 0.69314718056f);
#endif
}

__device__ __forceinline__ unsigned short fbf(float f) {
  union { float f; unsigned u; } x; x.f = f;
  unsigned r = x.u + 0x7fffu + ((x.u >> 16) & 1u);   // RNE
  return (unsigned short)(r >> 16);
}

static __device__ __forceinline__ bf16x4 pack2(unsigned lo, unsigned hi) {
  union { unsigned u[2]; bf16x4 v; } x; x.u[0] = lo; x.u[1] = hi; return x.v;
}

static __device__ __forceinline__ bf16x8 cat2(bf16x4 lo, bf16x4 hi) {
  union { bf16x4 h[2]; bf16x8 v; } x; x.h[0] = lo; x.h[1] = hi; return x.v;
}

// exp2 on 4 S-values, round to bf16, apply 4 mask bits (pre-shifted word), pack to bf16x4
static __device__ __forceinline__ bf16x4 epp(f32x4 s, unsigned pre, int sh) {
  union { float f; unsigned u; } e0, e1, e2, e3;
  e0.f = fast_exp2(s[0]); e1.f = fast_exp2(s[1]);
  e2.f = fast_exp2(s[2]); e3.f = fast_exp2(s[3]);
  unsigned p01 = __builtin_amdgcn_perm(e1.u + 0x8000u, e0.u + 0x8000u, 0x07060302u);
  unsigned p23 = __builtin_amdgcn_perm(e3.u + 0x8000u, e2.u + 0x8000u, 0x07060302u);
  int m0 = __builtin_amdgcn_sbfe(pre, sh + 0, 1), m1 = __builtin_amdgcn_sbfe(pre, sh + 1, 1);
  int m2 = __builtin_amdgcn_sbfe(pre, sh + 2, 1), m3 = __builtin_amdgcn_sbfe(pre, sh + 3, 1);
  unsigned k01 = __builtin_amdgcn_perm((unsigned)m1, (unsigned)m0, 0x07060100u);
  unsigned k23 = __builtin_amdgcn_perm((unsigned)m3, (unsigned)m2, 0x07060100u);
  return pack2(p01 & k01, p23 & k23);
}

// ---------------- merged fp32 -> bf16 convert pass: q,k,v (8192x3 blocks) + 4 weights ----------------
__global__ __launch_bounds__(256) void prep_kernel(const float* __restrict__ s0,
                                                   const float* __restrict__ s1,
                                                   const float* __restrict__ s2,
                                                   const float* __restrict__ w0,
                                                   const float* __restrict__ w1,
                                                   const float* __restrict__ w2,
                                                   const float* __restrict__ w3,
                                                   unsigned short* __restrict__ d0,
                                                   unsigned short* __restrict__ d1,
                                                   unsigned short* __restrict__ d2,
                                                   unsigned short* __restrict__ e0,
                                                   unsigned short* __restrict__ e1,
                                                   unsigned short* __restrict__ e2,
                                                   unsigned short* __restrict__ e3) {
  int bid = blockIdx.x;
  const float* s;
  unsigned short* d;
  int i;
  if (bid < 24576) {  // q,k,v: 3 x 8192 blocks
    int z = bid >> 13;
    s = (z == 0) ? s0 : (z == 1) ? s1 : s2;
    d = (z == 0) ? d0 : (z == 1) ? d1 : d2;
    i = (bid & 8191) * 256 + threadIdx.x;
  } else {            // weights: 4 x 1024 blocks
    int r = bid - 24576;
    int z = r >> 10;
    s = (z == 0) ? w0 : (z == 1) ? w1 : (z == 2) ? w2 : w3;
    d = (z == 0) ? e0 : (z == 1) ? e1 : (z == 2) ? e2 : e3;
    i = (r & 1023) * 256 + threadIdx.x;
  }
  float4 v = ((const float4*)s)[i];
  ushort4 o;
  o.x = fbf(v.x); o.y = fbf(v.y); o.z = fbf(v.z); o.w = fbf(v.w);
  ((ushort4*)d)[i] = o;
}

// ---------------- fused: V transpose (2048 blocks) + mask bit-pack (16384 blocks) ----------------
// Both independent, both run between proj and flash; fusing overlaps their memory traffic
// and removes one launch boundary. mbits aliases kbf (dead after proj).
__global__ __launch_bounds__(256) void vtm_kernel(const unsigned short* __restrict__ Vf,
                                                  unsigned short* __restrict__ Vt,
                                                  const int* __restrict__ m,
                                                  unsigned long long* __restrict__ o) {
  __shared__ unsigned short T[64][72];
  const int bid = blockIdx.x;
  const int tid = threadIdx.x;
  if (bid < 2048) {
    // V [B,H,S',Dh] -> Vt [B,H,Dh,S'] 64x64 tile transpose through LDS
    const int bh = bid >> 5;
    const int s0 = (bid & 31) * 64;
    {
      int r = tid >> 2, c = (tid & 3) * 16;
      const unsigned short* src = Vf + bh * 131072 + (s0 + r) * 64 + c;
      uint4 v0 = *(const uint4*)(src);
      uint4 v1 = *(const uint4*)(src + 8);
      *(uint4*)&T[r][c] = v0;
      *(uint4*)&T[r][c + 8] = v1;
    }
    __syncthreads();
    {
      int dh = tid & 63, rb = (tid >> 6) * 16;
      unsigned short ob[16];
#pragma unroll
      for (int j = 0; j < 16; ++j) ob[j] = T[rb + j][dh];
      unsigned short* dst = Vt + bh * 131072 + dh * 2048 + s0 + rb;
      *(uint4*)dst = *(const uint4*)&ob[0];
      *(uint4*)(dst + 8) = *(const uint4*)&ob[8];
    }
  } else {
    // mask int32 -> bitmask, kt-major: o[(kt*8192+row)*2 + h]; 4 chunks of 256 per block
    const int r = bid - 2048;
#pragma unroll
    for (int it = 0; it < 4; ++it) {
      int i = (r * 4 + it) * 256 + tid;
      unsigned long long b = __ballot(m[i] != 0);
      if ((tid & 63) == 0) {
        int row = i >> 11;          // [B*S) row index
        int kt = (i >> 7) & 15;     // 128-kcol tile
        int h = (i >> 6) & 1;       // ull half within tile
        o[(kt * 8192 + row) * 2 + h] = b;
      }
    }
  }
}

// ---------------- fused projections: C = A * W^T for z in {Q,K,V} ----------------
// Plain 2-barrier BK=32 structure — measured-best after 4 failed restructurings
// (reg-stage R3, BK64+swizzle R5, dbuf R7, fp32-LDS R2). Do not pipeline without
// the full 8-phase schedule.
// z=0: Qf bf16 scaled by log2(e)/8 ; z=1: Kf ; z=2: Vnat (natural layout; pure reshape)
__global__ __launch_bounds__(256) void proj_kernel(const unsigned short* __restrict__ A0,
                                                   const unsigned short* __restrict__ A1,
                                                   const unsigned short* __restrict__ A2,
                                                   const unsigned short* __restrict__ W0,
                                                   const unsigned short* __restrict__ W1,
                                                   const unsigned short* __restrict__ W2,
                                                   unsigned short* __restrict__ C0,
                                                   unsigned short* __restrict__ C1,
                                                   unsigned short* __restrict__ C2) {
  __shared__ unsigned short Alds[128 * 32];
  __shared__ unsigned short Blds[128 * 32];
  // XCD-aware swizzle: nwg = 1536 -> wid = (flat%8)*192 + flat/8 (by-strips stay on one XCD)
  const int flat = (blockIdx.z * 64 + blockIdx.y) * 8 + blockIdx.x;
  const int wid = (flat & 7) * 192 + (flat >> 3);
  const int z = wid >> 9;
  const int by = (wid >> 3) & 63;
  const int bx = wid & 7;
  const unsigned short* A = (z == 0) ? A0 : (z == 1) ? A1 : A2;
  const unsigned short* B = (z == 0) ? W0 : (z == 1) ? W1 : W2;
  const int tid = threadIdx.x;
  const int w = tid >> 6, l = tid & 63, q4 = l >> 4, c16 = l & 15;
  const int wm = w & 1, wn = w >> 1;
  const int mBase = by * 128, nBase = bx * 128;

  f32x4 acc[4][4];
#pragma unroll
  for (int a0 = 0; a0 < 4; ++a0)
#pragma unroll
    for (int a1 = 0; a1 < 4; ++a1) acc[a0][a1] = (f32x4){0.f, 0.f, 0.f, 0.f};

  const int r0 = tid >> 2, cc0 = tid & 3;

  for (int kt = 0; kt < 32; ++kt) {
    __syncthreads();
    const unsigned short* ga0 = A + (mBase + r0) * 1024 + kt * 32 + cc0 * 8;
    const unsigned short* ga1 = A + (mBase + 64 + r0) * 1024 + kt * 32 + cc0 * 8;
    const unsigned short* gb0 = B + (nBase + r0) * 1024 + kt * 32 + cc0 * 8;
    const unsigned short* gb1 = B + (nBase + 64 + r0) * 1024 + kt * 32 + cc0 * 8;
    GLDS16(ga0, &Alds[tid * 8]);
    GLDS16(ga1, &Alds[(tid + 256) * 8]);
    GLDS16(gb0, &Blds[tid * 8]);
    GLDS16(gb1, &Blds[(tid + 256) * 8]);
    __syncthreads();

    bf16x8 af[4], bfr[4];
#pragma unroll
    for (int mi = 0; mi < 4; ++mi)
      af[mi] = *(const bf16x8*)&Alds[(wm * 64 + mi * 16 + c16) * 32 + q4 * 8];
#pragma unroll
    for (int ni = 0; ni < 4; ++ni)
      bfr[ni] = *(const bf16x8*)&Blds[(wn * 64 + ni * 16 + c16) * 32 + q4 * 8];
#pragma unroll
    for (int mi = 0; mi < 4; ++mi)
#pragma unroll
      for (int ni = 0; ni < 4; ++ni) acc[mi][ni] = MFMA32(af[mi], bfr[ni], acc[mi][ni]);
  }

  unsigned short* C = (z == 0) ? C0 : (z == 1) ? C1 : C2;
  const float scale = (z == 0) ? 0.18033688f : 1.0f;  // log2(e)/8 folded into Q
#pragma unroll
  for (int mi = 0; mi < 4; ++mi) {
#pragma unroll
    for (int ni = 0; ni < 4; ++ni) {
#pragma unroll
      for (int rg = 0; rg < 4; ++rg) {
        int row = mBase + wm * 64 + mi * 16 + q4 * 4 + rg;
        int col = nBase + wn * 64 + ni * 16 + c16;
        C[row * 1024 + col] = fbf(acc[mi][ni][rg] * scale);
      }
    }
  }
}

// ---------------- final GEMM: out = Cws * fc_w^T + bias (fp32 out) ----------------
__global__ __launch_bounds__(256) void gemm_out(const unsigned short* __restrict__ A,
                                                const unsigned short* __restrict__ B,
                                                float* __restrict__ C,
                                                const float* __restrict__ bias) {
  __shared__ unsigned short Alds[128 * 32];
  __shared__ unsigned short Blds[128 * 32];
  const int flat = blockIdx.y * 8 + blockIdx.x;
  const int wid = (flat & 7) * 64 + (flat >> 3);
  const int by = wid >> 3, bx = wid & 7;
  const int tid = threadIdx.x;
  const int w = tid >> 6, l = tid & 63, q4 = l >> 4, c16 = l & 15;
  const int wm = w & 1, wn = w >> 1;
  const int mBase = by * 128, nBase = bx * 128;

  f32x4 acc[4][4];
#pragma unroll
  for (int a0 = 0; a0 < 4; ++a0)
#pragma unroll
    for (int a1 = 0; a1 < 4; ++a1) acc[a0][a1] = (f32x4){0.f, 0.f, 0.f, 0.f};

  const int r0 = tid >> 2, cc0 = tid & 3;

  for (int kt = 0; kt < 32; ++kt) {
    __syncthreads();
    const unsigned short* ga0 = A + (mBase + r0) * 1024 + kt * 32 + cc0 * 8;
    const unsigned short* ga1 = A + (mBase + 64 + r0) * 1024 + kt * 32 + cc0 * 8;
    const unsigned short* gb0 = B + (nBase + r0) * 1024 + kt * 32 + cc0 * 8;
    const unsigned short* gb1 = B + (nBase + 64 + r0) * 1024 + kt * 32 + cc0 * 8;
    GLDS16(ga0, &Alds[tid * 8]);
    GLDS16(ga1, &Alds[(tid + 256) * 8]);
    GLDS16(gb0, &Blds[tid * 8]);
    GLDS16(gb1, &Blds[(tid + 256) * 8]);
    __syncthreads();

    bf16x8 af[4], bfr[4];
#pragma unroll
    for (int mi = 0; mi < 4; ++mi)
      af[mi] = *(const bf16x8*)&Alds[(wm * 64 + mi * 16 + c16) * 32 + q4 * 8];
#pragma unroll
    for (int ni = 0; ni < 4; ++ni)
      bfr[ni] = *(const bf16x8*)&Blds[(wn * 64 + ni * 16 + c16) * 32 + q4 * 8];
#pragma unroll
    for (int mi = 0; mi < 4; ++mi)
#pragma unroll
      for (int ni = 0; ni < 4; ++ni) acc[mi][ni] = MFMA32(af[mi], bfr[ni], acc[mi][ni]);
  }

#pragma unroll
  for (int mi = 0; mi < 4; ++mi) {
#pragma unroll
    for (int ni = 0; ni < 4; ++ni) {
#pragma unroll
      for (int rg = 0; rg < 4; ++rg) {
        int row = mBase + wm * 64 + mi * 16 + q4 * 4 + rg;
        int col = nBase + wn * 64 + ni * 16 + c16;
        C[row * 1024 + col] = acc[mi][ni][rg] + bias[col];
      }
    }
  }
}

// ---------------- flash attention per (b, h, 128-row q tile) ----------------
// S^T = K·Q^T (P stays in registers); O^T = Vt·P^T with K=32 MFMA via k-permutation:
// lane q4 natively holds kcols {32m+4q4+j, 32m+16+4q4+j}; Vt A-frag loads the
// sigma-matched pair of b64s. Row sums via constant ones A-frag (permutation-invariant).
__global__ __launch_bounds__(256, 4) void flash_kernel(const unsigned short* __restrict__ Q,
                                                       const unsigned short* __restrict__ K,
                                                       const unsigned short* __restrict__ Vt,
                                                       const uint4* __restrict__ mb,
                                                       unsigned short* __restrict__ Cws,
                                                       float* __restrict__ res2) {
  __shared__ unsigned short Klds[128 * 64];   // [kcol][granule ^ (kcol&7)]
  __shared__ unsigned short Vtlds[64 * 128];  // [dh][granule ^ (dh&15)]
  const int tid = threadIdx.x;
  const int w = tid >> 6, l = tid & 63, q4 = l >> 4, c16 = l & 15;
  const int q44 = q4 * 4;
  // XCD swizzle: nwg = 1024 -> wid = (flat%8)*128 + flat/8 ; qt-groups (shared K/V) co-XCD
  const int flat = (blockIdx.z * 16 + blockIdx.y) * 16 + blockIdx.x;
  const int wid = (flat & 7) * 128 + (flat >> 3);
  const int qt = wid & 15, h = (wid >> 4) & 15, b = wid >> 8;
  const unsigned short* Qh = Q + (b * 2048 + h * 128) * 1024;
  const unsigned short* Kh = K + (b * 2048 + h * 128) * 1024;
  const unsigned short* Vth = Vt + (b * 16 + h) * 64 * 2048;

  // Q B-frags in registers for all 16 K-tiles
  bf16x8 qf[2][2];
#pragma unroll
  for (int i = 0; i < 2; ++i)
#pragma unroll
    for (int kc = 0; kc < 2; ++kc)
      qf[i][kc] = *(const bf16x8*)(Qh + (qt * 128 + w * 32 + i * 16 + c16) * 64 + kc * 32 + q4 * 8);

  const int rowi = b * 2048 + qt * 128 + w * 32 + c16;  // mask row, i=0 (i=1: +16)

  // staging lane offsets (global side carries the swizzle; LDS side is lane-linear)
  const int kOff = (tid >> 3) * 64 + (((tid & 7) ^ ((tid >> 3) & 7)) * 8);
  const int vOff = (tid >> 4) * 2048 + (((tid & 15) ^ (tid >> 4)) * 8);

  // QK read lane base: row=16n+c16, phys granule q4^(c16&7) (content = global granule q4)
  const int kb0 = c16 * 64 + ((q4 ^ (c16 & 7)) * 8);
  const int kb1 = kb0 ^ 32;
  // PV read: row=16t+c16, global granule gLo=4m+(q4>>1) (hi: +2), phys = g ^ c16, half q4&1
  const int vb = c16 * 128 + (q4 & 1) * 4;
  const int q41 = q4 >> 1;

  const bf16x8 ones8 = {(short)0x3F80, (short)0x3F80, (short)0x3F80, (short)0x3F80,
                        (short)0x3F80, (short)0x3F80, (short)0x3F80, (short)0x3F80};

  f32x4 oacc[2][4], soacc[2];
#pragma unroll
  for (int i = 0; i < 2; ++i) {
    soacc[i] = (f32x4){0.f, 0.f, 0.f, 0.f};
#pragma unroll
    for (int t = 0; t < 4; ++t) oacc[i][t] = (f32x4){0.f, 0.f, 0.f, 0.f};
  }

  for (int kt = 0; kt < 16; ++kt) {
    const unsigned short* gk = Kh + kt * 8192 + kOff;
    const unsigned short* gv = Vth + kt * 128 + vOff;
#pragma unroll
    for (int j = 0; j < 4; ++j) {
      GLDS16(gk + j * 2048, &Klds[(j * 256 + tid) * 8]);
      GLDS16(gv + j * 32768, &Vtlds[(j * 256 + tid) * 8]);
    }
    // coalesced kt-major mask load (overlaps the DMA)
    uint4 m0 = mb[kt * 8192 + rowi];
    uint4 m1 = mb[kt * 8192 + rowi + 16];
    unsigned pre0[4] = {m0.x >> q44, m0.y >> q44, m0.z >> q44, m0.w >> q44};
    unsigned pre1[4] = {m1.x >> q44, m1.y >> q44, m1.z >> q44, m1.w >> q44};
    __syncthreads();

#pragma unroll
    for (int m = 0; m < 4; ++m) {  // pair of 16-kcol chunks: n = 2m, 2m+1
      bf16x8 kfE0 = *(const bf16x8*)(Klds + kb0 + (2 * m) * 1024);
      bf16x8 kfE1 = *(const bf16x8*)(Klds + kb1 + (2 * m) * 1024);
      bf16x8 kfO0 = *(const bf16x8*)(Klds + kb0 + (2 * m + 1) * 1024);
      bf16x8 kfO1 = *(const bf16x8*)(Klds + kb1 + (2 * m + 1) * 1024);
      f32x4 sE0 = {0.f, 0.f, 0.f, 0.f}, sE1 = {0.f, 0.f, 0.f, 0.f};
      f32x4 sO0 = {0.f, 0.f, 0.f, 0.f}, sO1 = {0.f, 0.f, 0.f, 0.f};
      sE0 = MFMA32(kfE0, qf[0][0], sE0); sE0 = MFMA32(kfE1, qf[0][1], sE0);
      sE1 = MFMA32(kfE0, qf[1][0], sE1); sE1 = MFMA32(kfE1, qf[1][1], sE1);
      sO0 = MFMA32(kfO0, qf[0][0], sO0); sO0 = MFMA32(kfO1, qf[0][1], sO0);
      sO1 = MFMA32(kfO0, qf[1][0], sO1); sO1 = MFMA32(kfO1, qf[1][1], sO1);

      int shE = 0, shO = 16;  // kcol bit position within 32-bit mask word m
      bf16x8 pf0 = cat2(epp(sE0, pre0[m], shE), epp(sO0, pre0[m], shO));
      bf16x8 pf1 = cat2(epp(sE1, pre1[m], shE), epp(sO1, pre1[m], shO));

      int pLo = (4 * m + q41) ^ c16;
      int aLo = vb + pLo * 8;
#pragma unroll
      for (int t = 0; t < 4; ++t) {
        bf16x4 vlo = *(const bf16x4*)(Vtlds + aLo + t * 2048);
        bf16x4 vhi = *(const bf16x4*)(Vtlds + (aLo ^ 16) + t * 2048);
        bf16x8 vf8 = cat2(vlo, vhi);
        oacc[0][t] = MFMA32(vf8, pf0, oacc[0][t]);
        oacc[1][t] = MFMA32(vf8, pf1, oacc[1][t]);
      }
      soacc[0] = MFMA32(ones8, pf0, soacc[0]);
      soacc[1] = MFMA32(ones8, pf1, soacc[1]);
    }
    __syncthreads();
  }

  // epilogue: lane (c16,q4) holds O[q=base+i*16+c16][dh=16t+q44+rg]; soacc = rowsum(q)
#pragma unroll
  for (int i = 0; i < 2; ++i) {
    float sum = soacc[i][0];
    float rcp = (sum > 0.f) ? (1.0f / sum) : 0.f;  // sum==0 -> 0 reproduces NaN->0
    int q = qt * 128 + w * 32 + i * 16 + c16;
    float* rp = res2 + (((h * 4 + b) * 2048 + q) * 64 + q44);
    unsigned short* cp = Cws + ((b * 2048 + q) * 1024 + h * 64 + q44);
#pragma unroll
    for (int t = 0; t < 4; ++t) {
      float o0 = oacc[i][t][0] * rcp, o1 = oacc[i][t][1] * rcp;
      float o2 = oacc[i][t][2] * rcp, o3 = oacc[i][t][3] * rcp;
      float4 fo = {o0, o1, o2, o3};
      *(float4*)(rp + t * 16) = fo;
      ushort4 cv = {fbf(o0), fbf(o1), fbf(o2), fbf(o3)};
      *(ushort4*)(cp + t * 16) = cv;
    }
  }
}

extern "C" void kernel_launch(void* const* d_in, const int* in_sizes, int n_in,
                              void* d_out, int out_size, void* d_ws, size_t ws_size,
                              hipStream_t stream) {
  const float* query = (const float*)d_in[0];
  const float* key_t = (const float*)d_in[1];
  const float* value = (const float*)d_in[2];
  const int* mask = (const int*)d_in[3];
  const float* Wq = (const float*)d_in[4];
  const float* Wk = (const float*)d_in[5];
  const float* Wv = (const float*)d_in[6];
  const float* fcw = (const float*)d_in[7];
  const float* fcb = (const float*)d_in[8];
  float* out = (float*)d_out;

  char* ws = (char*)d_ws;
  unsigned short* qbf = (unsigned short*)(ws);                      // 16MB (later: Cws)
  unsigned short* kbf = (unsigned short*)(ws + (16u << 20));        // 16MB (later: mask bits)
  unsigned short* vbf = (unsigned short*)(ws + (32u << 20));        // 16MB (later: Vt)
  unsigned short* wqb = (unsigned short*)(ws + (48u << 20));        // 2MB
  unsigned short* wkb = (unsigned short*)(ws + (50u << 20));
  unsigned short* wvb = (unsigned short*)(ws + (52u << 20));
  unsigned short* fwb = (unsigned short*)(ws + (54u << 20));
  unsigned short* Qf = (unsigned short*)(ws + (56u << 20));         // 16MB
  unsigned short* Kf = (unsigned short*)(ws + (72u << 20));         // 16MB
  unsigned short* Vnat = (unsigned short*)(ws + (88u << 20));       // 16MB; total 104MB
  unsigned short* Cws = qbf;                                        // alias (qbf dead after proj)
  unsigned long long* mbits = (unsigned long long*)kbf;             // alias (kbf dead after proj)
  unsigned short* Vt = vbf;                                         // alias (vbf dead after proj)

  prep_kernel<<<28672, 256, 0, stream>>>(query, key_t, value, Wq, Wk, Wv, fcw,
                                         qbf, kbf, vbf, wqb, wkb, wvb, fwb);

  proj_kernel<<<dim3(8, 64, 3), 256, 0, stream>>>(qbf, kbf, vbf, wqb, wkb, wvb,
                                                  Qf, Kf, Vnat);

  vtm_kernel<<<18432, 256, 0, stream>>>(Vnat, Vt, mask, mbits);

  flash_kernel<<<dim3(16, 16, 4), 256, 0, stream>>>(Qf, Kf, Vt, (const uint4*)mbits, Cws,
                                                    out + 8388608);

  gemm_out<<<dim3(8, 64), 256, 0, stream>>>(Cws, fwb, out, fcb);
}